// Round 5
// baseline (112.134 us; speedup 1.0000x reference)
//
#include <hip/hip_runtime.h>
#include <hip/hip_bf16.h>

// x: [32,128,32,32] f32 -> N=32768 positions, D=128; emb: [512,128] f32.
// d_out: out0 quantized_st (4194304) | loss (1) | indices (32768) | usage (1)
//
// NUMERICS ARE CORRECTNESS-CRITICAL (verified passing in rounds 2/4):
//  - esq/fsq: numpy pairwise 8-accumulator pattern, squares rounded pre-sum
//  - dot: single sequential FMA chain over c = 0..127 ascending
//  - dist: s = fl( fl(fsq + esq) - 2*dot ), tie -> lowest index
//  - loss: dq f32; square f32; accumulate f64
// Do not change accumulation order.
//
// R5 change (perf only): code->lane assignment tx -> {4tx..4tx+3, 256+4tx..+3}
// so et reads are the canonical conflict-free b128 pattern (granule = lane),
// plus XOR column swizzle (q ^= (cl&7)<<2) to de-conflict staging writes.
// R4 counters showed SQ_LDS_BANK_CONFLICT=1.06e7 from the old tx*8 stride.

#define DCH    128
#define KCODES 512
#define NELEM  4194304
#define POSB   32          // positions per block
#define NBLK   1024        // 32768/32

#define OFF_LOSS  4194304
#define OFF_IDX   4194305
#define OFF_USAGE 4227073

// ws layout: flags 512*4 @0 | esq 512*4 @2048 | partials 1024*8 @4096

__device__ __forceinline__ float round_barrier(float v) {
    asm volatile("" : "+v"(v));
    return v;
}

// ---------------- prep: ||e_k||^2 (numpy order) + zero flags ----------------
__global__ __launch_bounds__(512) void vq_prep(const float* __restrict__ emb,
                                               float* __restrict__ esq,
                                               int* __restrict__ flags) {
    int k = threadIdx.x;
    const float* row = emb + (size_t)k * DCH;
    float r[8];
#pragma unroll
    for (int j = 0; j < 8; ++j) { float v = row[j]; r[j] = round_barrier(v * v); }
#pragma unroll
    for (int i = 8; i < DCH; i += 8) {
#pragma unroll
        for (int j = 0; j < 8; ++j) {
            float v = row[i + j];
            float sq = round_barrier(v * v);
            r[j] += sq;
        }
    }
    esq[k] = ((r[0] + r[1]) + (r[2] + r[3])) + ((r[4] + r[5]) + (r[6] + r[7]));
    flags[k] = 0;
}

// ---------------- main: distances + argmin + gather/STE + loss partials ----
// 1024 blocks x 256 threads. Block: 32 positions vs all 512 codes.
// ty = wave (4 pos groups of 8), tx = lane. Lane owns codes {4tx..4tx+3} and
// {256+4tx..256+4tx+3}. acc[8][8]: i = position, j = 0..3 first quad, 4..7 second.
__global__ __launch_bounds__(256, 4) void vq_main(const float* __restrict__ x,
                                                  const float* __restrict__ emb,
                                                  const float* __restrict__ esq,
                                                  int* __restrict__ flags,
                                                  float* __restrict__ out0,
                                                  float* __restrict__ out_idx,
                                                  double* __restrict__ partials) {
    __shared__ __align__(16) float xt[16][32];      // 2 KB  (c-chunk x tile)
    __shared__ __align__(16) float et[16][512];     // 32 KB (c-chunk emb^T, XOR-swizzled cols)
    __shared__ float esq_s[KCODES];                 // 2 KB
    __shared__ float sfsq[POSB];
    __shared__ int   sbi[POSB];

    const int t   = threadIdx.x;
    const int n0  = blockIdx.x * POSB;
    const int b   = n0 >> 10;
    const int hw0 = n0 & 1023;
    const float* xb = x + (size_t)b * DCH * 1024 + hw0;

    // stage esq table
    esq_s[t]       = esq[t];
    esq_s[t + 256] = esq[t + 256];

    // fsq, numpy 8-accumulator: thread (p = t>>3, j = t&7) does r_j for pos p
    {
        const int p = t >> 3, j = t & 7;
        float r;
        {
            float v = xb[(size_t)j * 1024 + p];
            r = round_barrier(v * v);
        }
#pragma unroll
        for (int i = 1; i < 16; ++i) {
            float v = xb[(size_t)(8 * i + j) * 1024 + p];
            float sq = round_barrier(v * v);
            r += sq;
        }
        float (*sr)[POSB] = (float (*)[POSB]) & et[0][0];
        sr[j][p] = r;
    }
    __syncthreads();
    if (t < POSB) {
        float (*sr)[POSB] = (float (*)[POSB]) & et[0][0];
        sfsq[t] = ((sr[0][t] + sr[1][t]) + (sr[2][t] + sr[3][t]))
                + ((sr[4][t] + sr[5][t]) + (sr[6][t] + sr[7][t]));
    }

    const int ty = t >> 6;   // wave id = pos group
    const int tx = t & 63;   // lane

    float acc[8][8];
#pragma unroll
    for (int i = 0; i < 8; ++i)
#pragma unroll
        for (int j = 0; j < 8; ++j) acc[i][j] = 0.f;

    const int kst = t >> 2;   // staging: k lane base (coalesced emb reads)
    const int jst = t & 3;    // float4 slot within 16-c chunk

    for (int cc = 0; cc < 8; ++cc) {
        __syncthreads();  // prev compute done (and sr consumed at cc=0)

        // stage x chunk: xt[cl][p], cl = t>>4, p = (t&15)*2
        {
            const int cl = t >> 4;
            const int p2 = (t & 15) * 2;
            float2 v = *reinterpret_cast<const float2*>(
                xb + (size_t)(cc * 16 + cl) * 1024 + p2);
            *reinterpret_cast<float2*>(&xt[cl][p2]) = v;
        }
        // stage emb chunk transposed + XOR col swizzle: et[cl][k ^ ((cl&7)<<2)]
#pragma unroll
        for (int r = 0; r < 8; ++r) {
            const int k = kst + 64 * r;
            float4 v = *reinterpret_cast<const float4*>(
                emb + (size_t)k * DCH + cc * 16 + jst * 4);
            float va[4] = {v.x, v.y, v.z, v.w};
#pragma unroll
            for (int w = 0; w < 4; ++w) {
                const int cl = jst * 4 + w;
                et[cl][k ^ ((cl & 7) << 2)] = va[w];
            }
        }
        __syncthreads();

        // 8x8 register tile; x reads wave-uniform broadcasts; et reads
        // conflict-free b128 (granule = lane ^ uniform).
#pragma unroll
        for (int cl = 0; cl < 16; ++cl) {
            const int s = (cl & 7) << 2;   // compile-time per unrolled iter
            float4 xv0 = *reinterpret_cast<const float4*>(&xt[cl][ty * 8]);
            float4 xv1 = *reinterpret_cast<const float4*>(&xt[cl][ty * 8 + 4]);
            float4 ev0 = *reinterpret_cast<const float4*>(&et[cl][(tx * 4) ^ s]);
            float4 ev1 = *reinterpret_cast<const float4*>(&et[cl][256 + ((tx * 4) ^ s)]);
            float xa[8] = {xv0.x, xv0.y, xv0.z, xv0.w, xv1.x, xv1.y, xv1.z, xv1.w};
            float ea[8] = {ev0.x, ev0.y, ev0.z, ev0.w, ev1.x, ev1.y, ev1.z, ev1.w};
#pragma unroll
            for (int i = 0; i < 8; ++i)
#pragma unroll
                for (int j = 0; j < 8; ++j)
                    acc[i][j] = __builtin_fmaf(xa[i], ea[j], acc[i][j]);
        }
    }

    // fold distances + per-thread argmin (ascending global k within thread)
    float bd[8];
    int   bi[8];
#pragma unroll
    for (int i = 0; i < 8; ++i) { bd[i] = 3.4e38f; bi[i] = 0; }
#pragma unroll
    for (int j = 0; j < 8; ++j) {
        const int kg = (j < 4) ? (tx * 4 + j) : (256 + tx * 4 + (j - 4));
        const float eq = esq_s[kg];
#pragma unroll
        for (int i = 0; i < 8; ++i) {
            float A = sfsq[ty * 8 + i] + eq;   // rounds once (ulp ~1.5e-5)
            float s = A - 2.f * acc[i][j];     // 2*acc exact; rounds once
            if (s < bd[i]) { bd[i] = s; bi[i] = kg; }
        }
    }
    // 64-lane butterfly reduce, lexicographic (d, idx)
#pragma unroll
    for (int m = 1; m < 64; m <<= 1) {
#pragma unroll
        for (int i = 0; i < 8; ++i) {
            float d2 = __shfl_xor(bd[i], m, 64);
            int   i2 = __shfl_xor(bi[i], m, 64);
            if (d2 < bd[i] || (d2 == bd[i] && i2 < bi[i])) { bd[i] = d2; bi[i] = i2; }
        }
    }
    if (tx == 0) {
#pragma unroll
        for (int i = 0; i < 8; ++i) {
            const int p = ty * 8 + i;
            out_idx[n0 + p] = (float)bi[i];
            sbi[p] = bi[i];
            flags[bi[i]] = 1;   // benign same-value race
        }
    }
    __syncthreads();

    // fused gather + straight-through write + f64 loss partial
    double local = 0.0;
    {
        const int cl8 = t >> 3;          // 0..31 (c row base)
        const int p4  = (t & 7) * 4;     // 0..28
        const int i0 = sbi[p4], i1 = sbi[p4 + 1], i2 = sbi[p4 + 2], i3 = sbi[p4 + 3];
#pragma unroll
        for (int it = 0; it < 4; ++it) {
            const int c = it * 32 + cl8;
            float4 xv = *reinterpret_cast<const float4*>(xb + (size_t)c * 1024 + p4);
            float q0 = emb[(size_t)i0 * DCH + c];
            float q1 = emb[(size_t)i1 * DCH + c];
            float q2 = emb[(size_t)i2 * DCH + c];
            float q3 = emb[(size_t)i3 * DCH + c];
            float d0 = q0 - xv.x, d1 = q1 - xv.y, d2 = q2 - xv.z, d3 = q3 - xv.w;
            float4 o = {xv.x + d0, xv.y + d1, xv.z + d2, xv.w + d3};
            *reinterpret_cast<float4*>(
                out0 + (size_t)(b * DCH + c) * 1024 + hw0 + p4) = o;
            local += (double)(d0 * d0);
            local += (double)(d1 * d1);
            local += (double)(d2 * d2);
            local += (double)(d3 * d3);
        }
    }
    // block f64 reduce (reuse et)
    double* sd = reinterpret_cast<double*>(&et[0][0]);
    sd[t] = local;
    __syncthreads();
    for (int s = 128; s > 0; s >>= 1) {
        if (t < s) sd[t] += sd[t + s];
        __syncthreads();
    }
    if (t == 0) partials[blockIdx.x] = sd[0];
}

// ---------------- finalize: loss + usage ----------------
__global__ __launch_bounds__(512) void vq_final(const double* __restrict__ partials,
                                                const int* __restrict__ flags,
                                                float* __restrict__ out_loss,
                                                float* __restrict__ out_usage) {
    __shared__ double sd[512];
    __shared__ int    si[512];
    const int t = threadIdx.x;
    double s = partials[t] + partials[t + 512];
    sd[t] = s;
    si[t] = flags[t];
    __syncthreads();
    for (int k = 256; k > 0; k >>= 1) {
        if (t < k) { sd[t] += sd[t + k]; si[t] += si[t + k]; }
        __syncthreads();
    }
    if (t == 0) {
        float m = (float)(sd[0] / (double)NELEM);
        *out_loss  = m + 0.25f * m;
        *out_usage = (float)si[0] / (float)KCODES;
    }
}

extern "C" void kernel_launch(void* const* d_in, const int* in_sizes, int n_in,
                              void* d_out, int out_size, void* d_ws, size_t ws_size,
                              hipStream_t stream) {
    const float* x   = (const float*)d_in[0];
    const float* emb = (const float*)d_in[1];
    float* out = (float*)d_out;

    float* out0      = out;
    float* out_loss  = out + OFF_LOSS;
    float* out_idx   = out + OFF_IDX;
    float* out_usage = out + OFF_USAGE;

    char* ws = (char*)d_ws;
    int*    ws_flags = (int*)ws;
    float*  ws_esq   = (float*)(ws + 2048);
    double* ws_part  = (double*)(ws + 4096);

    vq_prep <<<1,    512, 0, stream>>>(emb, ws_esq, ws_flags);
    vq_main <<<NBLK, 256, 0, stream>>>(x, emb, ws_esq, ws_flags, out0, out_idx, ws_part);
    vq_final<<<1,    512, 0, stream>>>(ws_part, ws_flags, out_loss, out_usage);
}

// Round 6
// 105.405 us; speedup vs baseline: 1.0638x; 1.0638x over previous
//
#include <hip/hip_runtime.h>
#include <hip/hip_bf16.h>

// x: [32,128,32,32] f32 -> N=32768 positions, D=128; emb: [512,128] f32.
// d_out: out0 quantized_st (4194304) | loss (1) | indices (32768) | usage (1)
//
// NUMERICS ARE CORRECTNESS-CRITICAL (verified passing in rounds 2/4/5):
//  - esq/fsq: numpy pairwise 8-accumulator pattern, squares rounded pre-sum
//  - dot: single sequential FMA chain over c = 0..127 ascending
//  - dist: s = fl( fl(fsq + esq) - 2*dot ), tie -> lowest index
//  - loss: dq f32; square f32; accumulate f64
// Do not change accumulation order.
//
// R6 change (perf only): __launch_bounds__(256,4) -> (256,2). R5 showed
// VGPR_Count=64 with a 64-float accumulator -> compiler parked acc in AGPRs
// (unified file) and shuttled via v_accvgpr_* every FMA, ~3x VALU ops.
// 27us FMA floor * ~3 = the measured 87us. Raising the VGPR cap removes the
// shuttle; LDS (37KB) still limits residency to 4 blocks/CU.

#define DCH    128
#define KCODES 512
#define NELEM  4194304
#define POSB   32          // positions per block
#define NBLK   1024        // 32768/32

#define OFF_LOSS  4194304
#define OFF_IDX   4194305
#define OFF_USAGE 4227073

// ws layout: flags 512*4 @0 | esq 512*4 @2048 | partials 1024*8 @4096

__device__ __forceinline__ float round_barrier(float v) {
    asm volatile("" : "+v"(v));
    return v;
}

// ---------------- prep: ||e_k||^2 (numpy order) + zero flags ----------------
__global__ __launch_bounds__(512) void vq_prep(const float* __restrict__ emb,
                                               float* __restrict__ esq,
                                               int* __restrict__ flags) {
    int k = threadIdx.x;
    const float* row = emb + (size_t)k * DCH;
    float r[8];
#pragma unroll
    for (int j = 0; j < 8; ++j) { float v = row[j]; r[j] = round_barrier(v * v); }
#pragma unroll
    for (int i = 8; i < DCH; i += 8) {
#pragma unroll
        for (int j = 0; j < 8; ++j) {
            float v = row[i + j];
            float sq = round_barrier(v * v);
            r[j] += sq;
        }
    }
    esq[k] = ((r[0] + r[1]) + (r[2] + r[3])) + ((r[4] + r[5]) + (r[6] + r[7]));
    flags[k] = 0;
}

// ---------------- main: distances + argmin + gather/STE + loss partials ----
// 1024 blocks x 256 threads. Block: 32 positions vs all 512 codes.
// ty = wave (4 pos groups of 8), tx = lane. Lane owns codes {4tx..4tx+3} and
// {256+4tx..256+4tx+3}. acc[8][8]: i = position, j = 0..3 first quad, 4..7 second.
__global__ __launch_bounds__(256, 2) void vq_main(const float* __restrict__ x,
                                                  const float* __restrict__ emb,
                                                  const float* __restrict__ esq,
                                                  int* __restrict__ flags,
                                                  float* __restrict__ out0,
                                                  float* __restrict__ out_idx,
                                                  double* __restrict__ partials) {
    __shared__ __align__(16) float xt[16][32];      // 2 KB  (c-chunk x tile)
    __shared__ __align__(16) float et[16][512];     // 32 KB (c-chunk emb^T, XOR-swizzled cols)
    __shared__ float esq_s[KCODES];                 // 2 KB
    __shared__ float sfsq[POSB];
    __shared__ int   sbi[POSB];

    const int t   = threadIdx.x;
    const int n0  = blockIdx.x * POSB;
    const int b   = n0 >> 10;
    const int hw0 = n0 & 1023;
    const float* xb = x + (size_t)b * DCH * 1024 + hw0;

    // stage esq table
    esq_s[t]       = esq[t];
    esq_s[t + 256] = esq[t + 256];

    // fsq, numpy 8-accumulator: thread (p = t>>3, j = t&7) does r_j for pos p
    {
        const int p = t >> 3, j = t & 7;
        float r;
        {
            float v = xb[(size_t)j * 1024 + p];
            r = round_barrier(v * v);
        }
#pragma unroll
        for (int i = 1; i < 16; ++i) {
            float v = xb[(size_t)(8 * i + j) * 1024 + p];
            float sq = round_barrier(v * v);
            r += sq;
        }
        float (*sr)[POSB] = (float (*)[POSB]) & et[0][0];
        sr[j][p] = r;
    }
    __syncthreads();
    if (t < POSB) {
        float (*sr)[POSB] = (float (*)[POSB]) & et[0][0];
        sfsq[t] = ((sr[0][t] + sr[1][t]) + (sr[2][t] + sr[3][t]))
                + ((sr[4][t] + sr[5][t]) + (sr[6][t] + sr[7][t]));
    }

    const int ty = t >> 6;   // wave id = pos group
    const int tx = t & 63;   // lane

    float acc[8][8];
#pragma unroll
    for (int i = 0; i < 8; ++i)
#pragma unroll
        for (int j = 0; j < 8; ++j) acc[i][j] = 0.f;

    const int kst = t >> 2;   // staging: k lane base (coalesced emb reads)
    const int jst = t & 3;    // float4 slot within 16-c chunk

    for (int cc = 0; cc < 8; ++cc) {
        __syncthreads();  // prev compute done (and sr consumed at cc=0)

        // stage x chunk: xt[cl][p], cl = t>>4, p = (t&15)*2
        {
            const int cl = t >> 4;
            const int p2 = (t & 15) * 2;
            float2 v = *reinterpret_cast<const float2*>(
                xb + (size_t)(cc * 16 + cl) * 1024 + p2);
            *reinterpret_cast<float2*>(&xt[cl][p2]) = v;
        }
        // stage emb chunk transposed + XOR col swizzle: et[cl][k ^ ((cl&7)<<2)]
#pragma unroll
        for (int r = 0; r < 8; ++r) {
            const int k = kst + 64 * r;
            float4 v = *reinterpret_cast<const float4*>(
                emb + (size_t)k * DCH + cc * 16 + jst * 4);
            float va[4] = {v.x, v.y, v.z, v.w};
#pragma unroll
            for (int w = 0; w < 4; ++w) {
                const int cl = jst * 4 + w;
                et[cl][k ^ ((cl & 7) << 2)] = va[w];
            }
        }
        __syncthreads();

        // 8x8 register tile; x reads wave-uniform broadcasts; et reads
        // conflict-free b128 (granule = lane ^ uniform).
#pragma unroll
        for (int cl = 0; cl < 16; ++cl) {
            const int s = (cl & 7) << 2;   // compile-time per unrolled iter
            float4 xv0 = *reinterpret_cast<const float4*>(&xt[cl][ty * 8]);
            float4 xv1 = *reinterpret_cast<const float4*>(&xt[cl][ty * 8 + 4]);
            float4 ev0 = *reinterpret_cast<const float4*>(&et[cl][(tx * 4) ^ s]);
            float4 ev1 = *reinterpret_cast<const float4*>(&et[cl][256 + ((tx * 4) ^ s)]);
            float xa[8] = {xv0.x, xv0.y, xv0.z, xv0.w, xv1.x, xv1.y, xv1.z, xv1.w};
            float ea[8] = {ev0.x, ev0.y, ev0.z, ev0.w, ev1.x, ev1.y, ev1.z, ev1.w};
#pragma unroll
            for (int i = 0; i < 8; ++i)
#pragma unroll
                for (int j = 0; j < 8; ++j)
                    acc[i][j] = __builtin_fmaf(xa[i], ea[j], acc[i][j]);
        }
    }

    // fold distances + per-thread argmin (ascending global k within thread)
    float bd[8];
    int   bi[8];
#pragma unroll
    for (int i = 0; i < 8; ++i) { bd[i] = 3.4e38f; bi[i] = 0; }
#pragma unroll
    for (int j = 0; j < 8; ++j) {
        const int kg = (j < 4) ? (tx * 4 + j) : (256 + tx * 4 + (j - 4));
        const float eq = esq_s[kg];
#pragma unroll
        for (int i = 0; i < 8; ++i) {
            float A = sfsq[ty * 8 + i] + eq;   // rounds once (ulp ~1.5e-5)
            float s = A - 2.f * acc[i][j];     // 2*acc exact; rounds once
            if (s < bd[i]) { bd[i] = s; bi[i] = kg; }
        }
    }
    // 64-lane butterfly reduce, lexicographic (d, idx)
#pragma unroll
    for (int m = 1; m < 64; m <<= 1) {
#pragma unroll
        for (int i = 0; i < 8; ++i) {
            float d2 = __shfl_xor(bd[i], m, 64);
            int   i2 = __shfl_xor(bi[i], m, 64);
            if (d2 < bd[i] || (d2 == bd[i] && i2 < bi[i])) { bd[i] = d2; bi[i] = i2; }
        }
    }
    if (tx == 0) {
#pragma unroll
        for (int i = 0; i < 8; ++i) {
            const int p = ty * 8 + i;
            out_idx[n0 + p] = (float)bi[i];
            sbi[p] = bi[i];
            flags[bi[i]] = 1;   // benign same-value race
        }
    }
    __syncthreads();

    // fused gather + straight-through write + f64 loss partial
    double local = 0.0;
    {
        const int cl8 = t >> 3;          // 0..31 (c row base)
        const int p4  = (t & 7) * 4;     // 0..28
        const int i0 = sbi[p4], i1 = sbi[p4 + 1], i2 = sbi[p4 + 2], i3 = sbi[p4 + 3];
#pragma unroll
        for (int it = 0; it < 4; ++it) {
            const int c = it * 32 + cl8;
            float4 xv = *reinterpret_cast<const float4*>(xb + (size_t)c * 1024 + p4);
            float q0 = emb[(size_t)i0 * DCH + c];
            float q1 = emb[(size_t)i1 * DCH + c];
            float q2 = emb[(size_t)i2 * DCH + c];
            float q3 = emb[(size_t)i3 * DCH + c];
            float d0 = q0 - xv.x, d1 = q1 - xv.y, d2 = q2 - xv.z, d3 = q3 - xv.w;
            float4 o = {xv.x + d0, xv.y + d1, xv.z + d2, xv.w + d3};
            *reinterpret_cast<float4*>(
                out0 + (size_t)(b * DCH + c) * 1024 + hw0 + p4) = o;
            local += (double)(d0 * d0);
            local += (double)(d1 * d1);
            local += (double)(d2 * d2);
            local += (double)(d3 * d3);
        }
    }
    // block f64 reduce (reuse et)
    double* sd = reinterpret_cast<double*>(&et[0][0]);
    sd[t] = local;
    __syncthreads();
    for (int s = 128; s > 0; s >>= 1) {
        if (t < s) sd[t] += sd[t + s];
        __syncthreads();
    }
    if (t == 0) partials[blockIdx.x] = sd[0];
}

// ---------------- finalize: loss + usage ----------------
__global__ __launch_bounds__(512) void vq_final(const double* __restrict__ partials,
                                                const int* __restrict__ flags,
                                                float* __restrict__ out_loss,
                                                float* __restrict__ out_usage) {
    __shared__ double sd[512];
    __shared__ int    si[512];
    const int t = threadIdx.x;
    double s = partials[t] + partials[t + 512];
    sd[t] = s;
    si[t] = flags[t];
    __syncthreads();
    for (int k = 256; k > 0; k >>= 1) {
        if (t < k) { sd[t] += sd[t + k]; si[t] += si[t + k]; }
        __syncthreads();
    }
    if (t == 0) {
        float m = (float)(sd[0] / (double)NELEM);
        *out_loss  = m + 0.25f * m;
        *out_usage = (float)si[0] / (float)KCODES;
    }
}

extern "C" void kernel_launch(void* const* d_in, const int* in_sizes, int n_in,
                              void* d_out, int out_size, void* d_ws, size_t ws_size,
                              hipStream_t stream) {
    const float* x   = (const float*)d_in[0];
    const float* emb = (const float*)d_in[1];
    float* out = (float*)d_out;

    float* out0      = out;
    float* out_loss  = out + OFF_LOSS;
    float* out_idx   = out + OFF_IDX;
    float* out_usage = out + OFF_USAGE;

    char* ws = (char*)d_ws;
    int*    ws_flags = (int*)ws;
    float*  ws_esq   = (float*)(ws + 2048);
    double* ws_part  = (double*)(ws + 4096);

    vq_prep <<<1,    512, 0, stream>>>(emb, ws_esq, ws_flags);
    vq_main <<<NBLK, 256, 0, stream>>>(x, emb, ws_esq, ws_flags, out0, out_idx, ws_part);
    vq_final<<<1,    512, 0, stream>>>(ws_part, ws_flags, out_loss, out_usage);
}